// Round 10
// baseline (71.656 us; speedup 1.0000x reference)
//
#include <hip/hip_runtime.h>
#include <hip/hip_bf16.h>

#define NELEM 16384
#define DIN 768
#define DMID 128
#define DOUT 4
#define NBWORDS 100000   // bitmap words: keys < 3.2e6 -> 100000 u32

typedef __attribute__((ext_vector_type(8))) short short8;
typedef __attribute__((ext_vector_type(4))) float f32x4;

__device__ __forceinline__ unsigned f2bf(float f) {
    unsigned u = __float_as_uint(f);
    return (u + 0x7FFFu + ((u >> 16) & 1u)) >> 16;   // RNE bf16
}

__device__ __forceinline__ unsigned aload(const unsigned* p) {
    return __hip_atomic_load((unsigned*)p, __ATOMIC_RELAXED, __HIP_MEMORY_SCOPE_AGENT);
}
__device__ __forceinline__ void astore(unsigned* p, unsigned v) {
    __hip_atomic_store(p, v, __ATOMIC_RELAXED, __HIP_MEMORY_SCOPE_AGENT);
}
__device__ __forceinline__ void aor(unsigned* p, unsigned v) {
    __hip_atomic_fetch_or(p, v, __ATOMIC_RELAXED, __HIP_MEMORY_SCOPE_AGENT);
}

// threshold barrier; counter zeroed by hipMemsetAsync each launch (proven R9).
__device__ __forceinline__ void gbar(unsigned* cnt, unsigned thresh) {
    __syncthreads();
    if (threadIdx.x == 0) {
        __hip_atomic_fetch_add(cnt, 1u, __ATOMIC_ACQ_REL, __HIP_MEMORY_SCOPE_AGENT);
        while (__hip_atomic_load(cnt, __ATOMIC_RELAXED, __HIP_MEMORY_SCOPE_AGENT) < thresh)
            __builtin_amdgcn_s_sleep(1);
        (void)__hip_atomic_load(cnt, __ATOMIC_ACQUIRE, __HIP_MEMORY_SCOPE_AGENT);
    }
    __syncthreads();
}

// ===========================================================================
// FAST2 ws layout:
//   Gb@0(64K) bitmap@65536(400000) PRE@465536(400000) btot@865536(256)
//   bar@865792(64) SD@865856(64K) WtG@931392(192K)  -> total 1,128,000
// SD[u] = b<<19 | start<<10 | len   (slot u's elements live in Gb[b*512+start ..))
// Gb word = vocab<<9 | s  (per-batch sorted, ascending)
// ===========================================================================
#define FAST2_WS 1128000

__global__ __launch_bounds__(256) void group_kernel(
    const int* __restrict__ vocab_ids, const float* __restrict__ W1,
    unsigned* __restrict__ Gb, unsigned* __restrict__ bitmap,
    unsigned* __restrict__ PRE, unsigned* __restrict__ btot,
    unsigned* __restrict__ SD, unsigned short* __restrict__ WtG,
    float* __restrict__ out_ids, unsigned* __restrict__ bar) {
    __shared__ unsigned S[512];
    __shared__ unsigned red[256];
    __shared__ unsigned wsumL[4];
    const int t = threadIdx.x;
    const int blk = blockIdx.x;
    const int lane = t & 63;
    const int wv = t >> 6;

    // ---- phase 0: zero bitmap (via coherent stores) + W1^T -> bf16 ----
    for (int w = blk * 256 + t; w < NBWORDS; w += 64 * 256) astore(&bitmap[w], 0u);
#pragma unroll
    for (int i = 0; i < 6; ++i) {
        int j = blk * 1536 + i * 256 + t;   // 0..98303
        int k = j >> 7;
        int c = j & 127;
        WtG[c * DIN + k] = (unsigned short)f2bf(W1[j]);
    }
    gbar(bar, 64);

    // ---- phase 1: blocks 0..31 sort batch blk in LDS; 32..63 mark bitmap ----
    if (blk < 32) {
        const int b = blk;
        S[t]       = ((unsigned)vocab_ids[b * 512 + t] << 9) | (unsigned)t;
        S[t + 256] = ((unsigned)vocab_ids[b * 512 + 256 + t] << 9) | (unsigned)(t + 256);
        const unsigned tu = (unsigned)t;
        for (unsigned k = 2; k <= 512; k <<= 1) {
            for (unsigned j = k >> 1; j > 0; j >>= 1) {
                __syncthreads();
                unsigned i = ((tu & ~(j - 1)) << 1) | (tu & (j - 1));
                unsigned p = i | j;
                bool asc = ((i & k) == 0);
                unsigned a = S[i], c = S[p];
                if ((a > c) == asc) { S[i] = c; S[p] = a; }
            }
        }
        __syncthreads();
        Gb[b * 512 + t] = S[t];
        Gb[b * 512 + 256 + t] = S[t + 256];
    } else {
        const int e0 = (blk - 32) * 512;
#pragma unroll
        for (int i = 0; i < 2; ++i) {
            int e = e0 + i * 256 + t;
            unsigned key = (unsigned)vocab_ids[e] * 32u + (unsigned)(e >> 9);
            aor(&bitmap[key >> 5], 1u << (key & 31u));
        }
    }
    gbar(bar, 128);

    // ---- phase 2: per-block popcount partial sums over bitmap chunk ----
    const int chunk = blk * 1563;
    const int lim = (chunk + 1563 < NBWORDS) ? chunk + 1563 : NBWORDS;
    {
        unsigned mysum = 0;
        for (int w = chunk + t; w < lim; w += 256) mysum += (unsigned)__popc(aload(&bitmap[w]));
        unsigned inc = mysum;
#pragma unroll
        for (int off = 1; off < 64; off <<= 1) {
            unsigned y = __shfl_up(inc, off);
            if (lane >= off) inc += y;
        }
        if (lane == 63) wsumL[wv] = inc;
        __syncthreads();
        if (t == 0) astore(&btot[blk], wsumL[0] + wsumL[1] + wsumL[2] + wsumL[3]);
        __syncthreads();
    }
    gbar(bar, 192);

    // ---- phase 3: exclusive scan -> PRE; compute U ----
    unsigned U = 0;
    {
        if (t < 64) red[t] = aload(&btot[t]);
        __syncthreads();
        unsigned base = 0;
#pragma unroll
        for (int j = 0; j < 64; ++j) {
            unsigned g = red[j];
            if (j < blk) base += g;
            U += g;
        }
        unsigned run = base;
        for (int r = 0; r < 7; ++r) {
            int w = chunk + r * 256 + t;
            unsigned pc = (w < lim) ? (unsigned)__popc(aload(&bitmap[w])) : 0u;
            unsigned inc = pc;
#pragma unroll
            for (int off = 1; off < 64; off <<= 1) {
                unsigned y = __shfl_up(inc, off);
                if (lane >= off) inc += y;
            }
            if (lane == 63) wsumL[wv] = inc;
            __syncthreads();
            unsigned wo = 0, rtot = 0;
#pragma unroll
            for (int i = 0; i < 4; ++i) {
                if (i < wv) wo += wsumL[i];
                rtot += wsumL[i];
            }
            if (w < lim) astore(&PRE[w], run + wo + inc - pc);
            run += rtot;
            __syncthreads();
        }
    }
    gbar(bar, 256);

    // ---- phase 4: blocks 0..31 emit runs; 32..63 pad slots >= U ----
    if (blk < 32) {
        const int b = blk;
        S[t] = Gb[b * 512 + t];
        S[t + 256] = Gb[b * 512 + 256 + t];
        __syncthreads();
#pragma unroll
        for (int q = 0; q < 2; ++q) {
            int i = q * 256 + t;
            unsigned wd = S[i];
            unsigned v = wd >> 9;
            bool flag = (i == 0) || ((S[i - 1] >> 9) != v);
            if (flag) {
                int end = i + 1;
                while (end < 512 && (S[end] >> 9) == v) ++end;
                unsigned len = (unsigned)(end - i);
                unsigned key = v * 32u + (unsigned)b;
                unsigned bw = key >> 5, bit = key & 31u;
                unsigned rank = aload(&PRE[bw]) +
                                (unsigned)__popc(aload(&bitmap[bw]) & ((1u << bit) - 1u));
                SD[rank] = ((unsigned)b << 19) | ((unsigned)i << 10) | len;
                out_ids[2 * rank + 0] = (float)v;
                out_ids[2 * rank + 1] = (float)b;
            }
        }
    } else {
        for (int u = (int)U + (blk - 32) * 256 + t; u < NELEM; u += 32 * 256) {
            SD[u] = 0u;
            out_ids[2 * u + 0] = 0.0f;
            out_ids[2 * u + 1] = 0.0f;
        }
    }
}

// ===========================================================================
// fused MFMA kernel (proven structure; gather now via SD + per-batch Gb).
// ===========================================================================
#define FBM 16
__global__ __launch_bounds__(256) void fused_kernel(
    const unsigned* __restrict__ Gb,
    const unsigned* __restrict__ SD,
    const unsigned short* __restrict__ WtG,
    const float* __restrict__ emb,
    const float* __restrict__ b1,
    const float* __restrict__ enc,
    float* __restrict__ out_enc) {
    __shared__ char smem[20736];

    const int t = threadIdx.x;
    const int u0 = blockIdx.x * FBM;
    const int l = t & 63;
    const int w = t >> 6;

    const int ar = t >> 4;
    const int ak4 = t & 15;
    const unsigned sdw = SD[u0 + ar];
    const int lenA = (int)(sdw & 1023u);
    const unsigned embBase = (sdw >> 19) << 9;                      // b*512
    const unsigned gb0 = embBase + ((sdw >> 10) & 511u);            // b*512+start

    f32x4 acc0 = {0.f, 0.f, 0.f, 0.f};
    f32x4 acc1 = {0.f, 0.f, 0.f, 0.f};

    for (int kk = 0; kk < DIN; kk += 64) {
        __syncthreads();
        {
            float s0 = 0.f, s1 = 0.f, s2 = 0.f, s3 = 0.f;
            const float* base = emb + (size_t)(kk + ak4 * 4);
            for (int p = 0; p < lenA; ++p) {
                unsigned idx = embBase + (Gb[gb0 + p] & 511u);
                const float4 e4 = *(const float4*)(base + (size_t)idx * DIN);
                s0 += e4.x; s1 += e4.y; s2 += e4.z; s3 += e4.w;
            }
            uint2 packed;
            packed.x = f2bf(s0) | (f2bf(s1) << 16);
            packed.y = f2bf(s2) | (f2bf(s3) << 16);
            *(uint2*)(smem + ar * 144 + ak4 * 8) = packed;
        }
        {
#pragma unroll
            for (int i = 0; i < 4; ++i) {
                int q = t + i * 256;
                int c = q >> 3;
                int uo = q & 7;
                uint4 dv = *(const uint4*)(WtG + (size_t)c * DIN + kk + uo * 8);
                *(uint4*)(smem + 2304 + c * 144 + uo * 16) = dv;
            }
        }
        __syncthreads();
        {
            const int arow = l & 15;
            const int ull = l >> 4;
#pragma unroll
            for (int kf = 0; kf < 2; ++kf) {
                short8 aF = *(const short8*)(smem + arow * 144 + kf * 64 + ull * 16);
                short8 bF0 = *(const short8*)(smem + 2304 + (w * 32 + arow) * 144 + kf * 64 + ull * 16);
                short8 bF1 = *(const short8*)(smem + 2304 + (w * 32 + 16 + arow) * 144 + kf * 64 + ull * 16);
                acc0 = __builtin_amdgcn_mfma_f32_16x16x32_bf16(aF, bF0, acc0, 0, 0, 0);
                acc1 = __builtin_amdgcn_mfma_f32_16x16x32_bf16(aF, bF1, acc1, 0, 0, 0);
            }
        }
    }
    __syncthreads();
    {
        float* Hs = (float*)smem;
        const int col0 = w * 32 + (l & 15);
        const int rbase = (l >> 4) * 4;
#pragma unroll
        for (int reg = 0; reg < 4; ++reg) {
            Hs[(rbase + reg) * 132 + col0] = tanhf(acc0[reg] + b1[col0]);
            Hs[(rbase + reg) * 132 + col0 + 16] = tanhf(acc1[reg] + b1[col0 + 16]);
        }
    }
    __syncthreads();
    {
        const float* Hs = (const float*)smem;
        const int r = t >> 4;
        const int g = t & 15;
        const int u = u0 + r;
        const unsigned sdw2 = SD[u];
        unsigned vocab = 0;
        if (sdw2 & 1023u)
            vocab = Gb[((sdw2 >> 19) << 9) + ((sdw2 >> 10) & 511u)] >> 9;
        const float4* wrow = (const float4*)(enc + (size_t)vocab * (DMID * DOUT));
        float ax = 0.f, ay = 0.f, az = 0.f, aw = 0.f;
#pragma unroll
        for (int jj = 0; jj < 8; ++jj) {
            int j = jj * 16 + g;
            float4 w4 = wrow[j];
            float hv = Hs[r * 132 + j];
            ax += hv * w4.x; ay += hv * w4.y; az += hv * w4.z; aw += hv * w4.w;
        }
#pragma unroll
        for (int off = 1; off < 16; off <<= 1) {
            ax += __shfl_xor(ax, off);
            ay += __shfl_xor(ay, off);
            az += __shfl_xor(az, off);
            aw += __shfl_xor(aw, off);
        }
        if (g == 0) {
            float4 o;
            o.x = 1.f / (1.f + expf(-ax));
            o.y = 1.f / (1.f + expf(-ay));
            o.z = 1.f / (1.f + expf(-az));
            o.w = 1.f / (1.f + expf(-aw));
            *(float4*)(out_enc + (size_t)u * 4) = o;
        }
    }
}

// ===========================================================================
// FALLBACK A (proven R9): mega sort via 3-pass radix + coop barriers.
// ===========================================================================
#define FAST_WS 557440
#define SB 64

__device__ __forceinline__ void aadd(unsigned* p, unsigned v) {
    __hip_atomic_fetch_add(p, v, __ATOMIC_RELAXED, __HIP_MEMORY_SCOPE_AGENT);
}

template <bool HASNEXT>
__device__ __forceinline__ void scatter_pass(
    const unsigned* __restrict__ src, unsigned* __restrict__ dst,
    const unsigned* __restrict__ histCur, unsigned* __restrict__ histNext,
    int shift, int nshift, int blk, int t,
    unsigned* base_lds, unsigned* whist, unsigned* wsum) {
    const int lane = t & 63;
    const int w = t >> 6;
    unsigned x = aload(&src[blk * 256 + t]);
    unsigned d = (x >> shift) & 255u;
    whist[t] = 0; whist[256 + t] = 0; whist[512 + t] = 0; whist[768 + t] = 0;
    unsigned rowsum = 0, myprefix = 0;
#pragma unroll
    for (int b = 0; b < SB; ++b) {
        unsigned h = aload(&histCur[b * 256 + t]);
        rowsum += h;
        if (b < blk) myprefix += h;
    }
    unsigned inc = rowsum;
#pragma unroll
    for (int off = 1; off < 64; off <<= 1) {
        unsigned y = __shfl_up(inc, off);
        if (lane >= off) inc += y;
    }
    if (lane == 63) wsum[w] = inc;
    __syncthreads();
    unsigned wo = 0;
    for (int w2 = 0; w2 < w; ++w2) wo += wsum[w2];
    base_lds[t] = wo + (inc - rowsum) + myprefix;
    unsigned long long m = ~0ull;
#pragma unroll
    for (int bit = 0; bit < 8; ++bit) {
        unsigned long long bb = __ballot((d >> bit) & 1u);
        m &= ((d >> bit) & 1u) ? bb : ~bb;
    }
    int inrank = __popcll(m & ((1ull << lane) - 1ull));
    if (inrank == 0) whist[w * 256 + d] = (unsigned)__popcll(m);
    __syncthreads();
    unsigned cross = 0;
    for (int w2 = 0; w2 < w; ++w2) cross += whist[w2 * 256 + d];
    unsigned dstpos = base_lds[d] + cross + (unsigned)inrank;
    astore(&dst[dstpos], x);
    if (HASNEXT) {
        unsigned dn = (x >> nshift) & 255u;
        aadd(&histNext[(dstpos >> 8) * 256 + dn], 1u);
    }
    __syncthreads();
}

__global__ __launch_bounds__(256) void sort_mega_kernel(
    const int* __restrict__ vocab_ids, const float* __restrict__ W1,
    unsigned* __restrict__ P0, unsigned* __restrict__ P1,
    unsigned* __restrict__ hist0, unsigned* __restrict__ hist1,
    unsigned* __restrict__ hist2,
    unsigned short* __restrict__ RS, unsigned short* __restrict__ WtG,
    float* __restrict__ out_ids,
    unsigned* __restrict__ bar, unsigned* __restrict__ gsum) {
    __shared__ unsigned base_lds[256];
    __shared__ unsigned whist[4 * 256];
    __shared__ unsigned wsum[4];
    const int t = threadIdx.x;
    const int blk = blockIdx.x;
    const int e = blk * 256 + t;
    {
        whist[t] = 0;
        unsigned word = ((unsigned)vocab_ids[e] << 14) | (unsigned)e;
        astore(&P0[e], word);
        __syncthreads();
        atomicAdd(&whist[(word >> 9) & 255u], 1u);
        __syncthreads();
        astore(&hist0[blk * 256 + t], whist[t]);
        astore(&hist1[blk * 256 + t], 0u);
        astore(&hist2[blk * 256 + t], 0u);
#pragma unroll
        for (int i = 0; i < 6; ++i) {
            int j = blk * 1536 + i * 256 + t;
            int k = j >> 7;
            int c = j & 127;
            WtG[c * DIN + k] = (unsigned short)f2bf(W1[j]);
        }
        __syncthreads();
    }
    gbar(bar, SB * 1);
    scatter_pass<true >(P0, P1, hist0, hist1, 9, 17, blk, t, base_lds, whist, wsum);
    gbar(bar, SB * 2);
    scatter_pass<true >(P1, P0, hist1, hist2, 17, 25, blk, t, base_lds, whist, wsum);
    gbar(bar, SB * 3);
    scatter_pass<false>(P0, P1, hist2, nullptr, 25, 0, blk, t, base_lds, whist, wsum);
    gbar(bar, SB * 4);
    unsigned word = aload(&P1[e]);
    unsigned key = word >> 9;
    bool f = (e == 0) || ((aload(&P1[e - 1]) >> 9) != key);
    {
        const int lane = t & 63;
        const int w = t >> 6;
        unsigned long long bb = __ballot(f ? 1 : 0);
        unsigned lrank = (unsigned)__popcll(bb & ((1ull << lane) - 1ull));
        if (lane == 0) wsum[w] = (unsigned)__popcll(bb);
        __syncthreads();
        unsigned woff = 0, btotv = 0;
#pragma unroll
        for (int w2 = 0; w2 < 4; ++w2) {
            if (w2 < w) woff += wsum[w2];
            btotv += wsum[w2];
        }
        if (t == 0) astore(&gsum[blk], btotv);
        gbar(bar, SB * 5);
        if (t < SB) base_lds[t] = aload(&gsum[t]);
        __syncthreads();
        unsigned prefix = 0, U = 0;
#pragma unroll
        for (int b = 0; b < SB; ++b) {
            unsigned g = base_lds[b];
            if (b < blk) prefix += g;
            U += g;
        }
        if (f) {
            unsigned r = prefix + woff + lrank;
            RS[r] = (unsigned short)e;
            out_ids[2 * r + 0] = (float)(word >> 14);
            out_ids[2 * r + 1] = (float)(key & 31u);
        }
        if ((unsigned)e >= U) {
            RS[e] = (unsigned short)NELEM;
            out_ids[2 * e + 0] = 0.0f;
            out_ids[2 * e + 1] = 0.0f;
        }
        if (e == 0) RS[NELEM] = (unsigned short)NELEM;
    }
}

// fused variant reading RS/G (for fallback paths) — R9-proven.
__global__ __launch_bounds__(256) void fused_kernel_rs(
    const unsigned* __restrict__ G,
    const unsigned short* __restrict__ RS,
    const unsigned short* __restrict__ WtG,
    const float* __restrict__ emb,
    const float* __restrict__ b1,
    const float* __restrict__ enc,
    float* __restrict__ out_enc) {
    __shared__ char smem[20736];
    const int t = threadIdx.x;
    const int u0 = blockIdx.x * FBM;
    const int l = t & 63;
    const int w = t >> 6;
    const int ar = t >> 4;
    const int ak4 = t & 15;
    const int rs_a = (int)RS[u0 + ar];
    const int re_a = (int)RS[u0 + ar + 1];
    f32x4 acc0 = {0.f, 0.f, 0.f, 0.f};
    f32x4 acc1 = {0.f, 0.f, 0.f, 0.f};
    for (int kk = 0; kk < DIN; kk += 64) {
        __syncthreads();
        {
            float s0 = 0.f, s1 = 0.f, s2 = 0.f, s3 = 0.f;
            const float* base = emb + (size_t)(kk + ak4 * 4);
            for (int p = rs_a; p < re_a; ++p) {
                unsigned idx = G[p] & 16383u;
                const float4 e4 = *(const float4*)(base + (size_t)idx * DIN);
                s0 += e4.x; s1 += e4.y; s2 += e4.z; s3 += e4.w;
            }
            uint2 packed;
            packed.x = f2bf(s0) | (f2bf(s1) << 16);
            packed.y = f2bf(s2) | (f2bf(s3) << 16);
            *(uint2*)(smem + ar * 144 + ak4 * 8) = packed;
        }
        {
#pragma unroll
            for (int i = 0; i < 4; ++i) {
                int q = t + i * 256;
                int c = q >> 3;
                int uo = q & 7;
                uint4 dv = *(const uint4*)(WtG + (size_t)c * DIN + kk + uo * 8);
                *(uint4*)(smem + 2304 + c * 144 + uo * 16) = dv;
            }
        }
        __syncthreads();
        {
            const int arow = l & 15;
            const int ull = l >> 4;
#pragma unroll
            for (int kf = 0; kf < 2; ++kf) {
                short8 aF = *(const short8*)(smem + arow * 144 + kf * 64 + ull * 16);
                short8 bF0 = *(const short8*)(smem + 2304 + (w * 32 + arow) * 144 + kf * 64 + ull * 16);
                short8 bF1 = *(const short8*)(smem + 2304 + (w * 32 + 16 + arow) * 144 + kf * 64 + ull * 16);
                acc0 = __builtin_amdgcn_mfma_f32_16x16x32_bf16(aF, bF0, acc0, 0, 0, 0);
                acc1 = __builtin_amdgcn_mfma_f32_16x16x32_bf16(aF, bF1, acc1, 0, 0, 0);
            }
        }
    }
    __syncthreads();
    {
        float* Hs = (float*)smem;
        const int col0 = w * 32 + (l & 15);
        const int rbase = (l >> 4) * 4;
#pragma unroll
        for (int reg = 0; reg < 4; ++reg) {
            Hs[(rbase + reg) * 132 + col0] = tanhf(acc0[reg] + b1[col0]);
            Hs[(rbase + reg) * 132 + col0 + 16] = tanhf(acc1[reg] + b1[col0 + 16]);
        }
    }
    __syncthreads();
    {
        const float* Hs = (const float*)smem;
        const int r = t >> 4;
        const int g = t & 15;
        const int u = u0 + r;
        const int rs = (int)RS[u];
        const int re = (int)RS[u + 1];
        unsigned vocab = (rs < re) ? (G[rs] >> 14) : 0u;
        const float4* wrow = (const float4*)(enc + (size_t)vocab * (DMID * DOUT));
        float ax = 0.f, ay = 0.f, az = 0.f, aw = 0.f;
#pragma unroll
        for (int jj = 0; jj < 8; ++jj) {
            int j = jj * 16 + g;
            float4 w4 = wrow[j];
            float hv = Hs[r * 132 + j];
            ax += hv * w4.x; ay += hv * w4.y; az += hv * w4.z; aw += hv * w4.w;
        }
#pragma unroll
        for (int off = 1; off < 16; off <<= 1) {
            ax += __shfl_xor(ax, off);
            ay += __shfl_xor(ay, off);
            az += __shfl_xor(az, off);
            aw += __shfl_xor(aw, off);
        }
        if (g == 0) {
            float4 o;
            o.x = 1.f / (1.f + expf(-ax));
            o.y = 1.f / (1.f + expf(-ay));
            o.z = 1.f / (1.f + expf(-az));
            o.w = 1.f / (1.f + expf(-aw));
            *(float4*)(out_enc + (size_t)u * 4) = o;
        }
    }
}

// ===========================================================================
// FALLBACK B (proven R6): single-block LDS sort + transpose.
// ===========================================================================
#define SORT_SMEM (65536 + 65536 + 4096 + 64)

__global__ __launch_bounds__(1024) void sort_transpose_kernel(
    const int* __restrict__ vocab_ids,
    const float* __restrict__ W1,
    unsigned int* __restrict__ G,
    unsigned short* __restrict__ RS,
    unsigned short* __restrict__ WtG,
    float* __restrict__ out_ids) {
    const int t = threadIdx.x;
    if (blockIdx.x != 0) {
        int idx = (blockIdx.x - 1) * 1024 + t;
        if (idx < DMID * DIN) {
            int c = idx / DIN;
            int k = idx - c * DIN;
            WtG[idx] = (unsigned short)f2bf(W1[k * DMID + c]);
        }
        return;
    }
    extern __shared__ char smem[];
    unsigned* Gs     = (unsigned*)smem;
    unsigned* histDM = (unsigned*)(smem + 65536);
    unsigned* sums   = (unsigned*)(smem + 131072);
    unsigned* totalU = (unsigned*)(smem + 135168);
    for (int e = t; e < NELEM; e += 1024)
        Gs[e] = ((unsigned)vocab_ids[e] << 14) | (unsigned)e;
    __syncthreads();
    for (int pass = 0; pass < 6; ++pass) {
        const int shift = 9 + pass * 4;
        unsigned v[16];
#pragma unroll
        for (int i = 0; i < 16; ++i) v[i] = Gs[t * 16 + i];
#pragma unroll
        for (int d = 0; d < 16; ++d) histDM[d * 1024 + t] = 0;
#pragma unroll
        for (int i = 0; i < 16; ++i) histDM[((v[i] >> shift) & 15u) * 1024 + t] += 1;
        __syncthreads();
        unsigned lex[16]; unsigned run = 0;
#pragma unroll
        for (int i = 0; i < 16; ++i) { unsigned x = histDM[t * 16 + i]; lex[i] = run; run += x; }
        sums[t] = run;
        __syncthreads();
        if (t < 64) {
            unsigned s[16]; unsigned tot = 0;
#pragma unroll
            for (int i = 0; i < 16; ++i) { unsigned x = sums[t * 16 + i]; s[i] = tot; tot += x; }
            unsigned incv = tot;
#pragma unroll
            for (int off = 1; off < 64; off <<= 1) {
                unsigned y = __shfl_up(incv, off);
                if (t >= off) incv += y;
            }
            unsigned excl = incv - tot;
#pragma unroll
            for (int i = 0; i < 16; ++i) sums[t * 16 + i] = excl + s[i];
        }
        __syncthreads();
#pragma unroll
        for (int i = 0; i < 16; ++i) histDM[t * 16 + i] = sums[t] + lex[i];
        __syncthreads();
        unsigned mycnt[16];
#pragma unroll
        for (int d = 0; d < 16; ++d) mycnt[d] = histDM[d * 1024 + t];
#pragma unroll
        for (int i = 0; i < 16; ++i) {
            unsigned d = (v[i] >> shift) & 15u;
            Gs[mycnt[d]++] = v[i];
        }
        __syncthreads();
    }
    unsigned v[16];
#pragma unroll
    for (int i = 0; i < 16; ++i) v[i] = Gs[t * 16 + i];
    unsigned pk = (t == 0) ? 0xFFFFFFFFu : (Gs[t * 16 - 1] >> 9);
    unsigned fm = 0;
#pragma unroll
    for (int i = 0; i < 16; ++i) {
        unsigned key = v[i] >> 9;
        if (key != pk) fm |= (1u << i);
        pk = key;
    }
    sums[t] = (unsigned)__popc(fm);
    __syncthreads();
    if (t < 64) {
        unsigned s[16]; unsigned tot = 0;
#pragma unroll
        for (int i = 0; i < 16; ++i) { unsigned x = sums[t * 16 + i]; s[i] = tot; tot += x; }
        unsigned incv = tot;
#pragma unroll
        for (int off = 1; off < 64; off <<= 1) {
            unsigned y = __shfl_up(incv, off);
            if (t >= off) incv += y;
        }
        unsigned excl = incv - tot;
#pragma unroll
        for (int i = 0; i < 16; ++i) sums[t * 16 + i] = excl + s[i];
        if (t == 63) *totalU = incv;
    }
    __syncthreads();
    unsigned r = sums[t];
#pragma unroll
    for (int i = 0; i < 16; ++i) {
        if (fm & (1u << i)) {
            RS[r] = (unsigned short)(t * 16 + i);
            out_ids[2 * r + 0] = (float)(v[i] >> 14);
            out_ids[2 * r + 1] = (float)((v[i] >> 9) & 31u);
            ++r;
        }
    }
    const unsigned U = *totalU;
    for (int u = t; u < NELEM; u += 1024) {
        if ((unsigned)u >= U) {
            RS[u] = (unsigned short)NELEM;
            out_ids[2 * u + 0] = 0.0f;
            out_ids[2 * u + 1] = 0.0f;
        }
        G[u] = Gs[u];
    }
    if (t == 0) RS[NELEM] = (unsigned short)NELEM;
}

// ---------------------------------------------------------------------------
extern "C" void kernel_launch(void* const* d_in, const int* in_sizes, int n_in,
                              void* d_out, int out_size, void* d_ws, size_t ws_size,
                              hipStream_t stream) {
    const int*   vocab_ids = (const int*)d_in[0];
    const float* emb       = (const float*)d_in[1];
    const float* W1        = (const float*)d_in[2];
    const float* b1        = (const float*)d_in[3];
    const float* enc       = (const float*)d_in[4];
    float* out = (float*)d_out;
    float* out_ids = out;
    float* out_enc = out + NELEM * 2;
    char* ws = (char*)d_ws;

    if (ws_size >= FAST2_WS) {
        unsigned*       Gb     = (unsigned*)(ws + 0);
        unsigned*       bitmap = (unsigned*)(ws + 65536);
        unsigned*       PRE    = (unsigned*)(ws + 465536);
        unsigned*       btot   = (unsigned*)(ws + 865536);
        unsigned*       bar    = (unsigned*)(ws + 865792);
        unsigned*       SD     = (unsigned*)(ws + 865856);
        unsigned short* WtG    = (unsigned short*)(ws + 931392);

        hipMemsetAsync(bar, 0, 4, stream);
        group_kernel<<<64, 256, 0, stream>>>(vocab_ids, W1, Gb, bitmap, PRE, btot,
                                             SD, WtG, out_ids, bar);
        fused_kernel<<<NELEM / FBM, 256, 0, stream>>>(Gb, SD, WtG, emb, b1, enc, out_enc);
    } else if (ws_size >= FAST_WS) {
        unsigned*       P0    = (unsigned*)(ws + 0);
        unsigned*       P1    = (unsigned*)(ws + 65536);
        unsigned*       hist0 = (unsigned*)(ws + 131072);
        unsigned*       hist1 = (unsigned*)(ws + 196608);
        unsigned*       hist2 = (unsigned*)(ws + 262144);
        unsigned short* RS    = (unsigned short*)(ws + 327680);
        unsigned short* WtG   = (unsigned short*)(ws + 360512);
        unsigned*       bar   = (unsigned*)(ws + 557120);
        unsigned*       gsum  = (unsigned*)(ws + 557184);

        hipMemsetAsync(bar, 0, 4, stream);
        sort_mega_kernel<<<SB, 256, 0, stream>>>(vocab_ids, W1, P0, P1,
                                                 hist0, hist1, hist2,
                                                 RS, WtG, out_ids, bar, gsum);
        fused_kernel_rs<<<NELEM / FBM, 256, 0, stream>>>(P1, RS, WtG, emb, b1, enc, out_enc);
    } else {
        unsigned int*   G   = (unsigned int*)(ws);
        unsigned short* RS  = (unsigned short*)(ws + 65536);
        unsigned short* WtG = (unsigned short*)(ws + 98432);

        hipFuncSetAttribute((const void*)sort_transpose_kernel,
                            hipFuncAttributeMaxDynamicSharedMemorySize, SORT_SMEM);
        sort_transpose_kernel<<<1 + 96, 1024, SORT_SMEM, stream>>>(
            vocab_ids, W1, G, RS, WtG, out_ids);
        fused_kernel_rs<<<NELEM / FBM, 256, 0, stream>>>(G, RS, WtG, emb, b1, enc, out_enc);
    }
}